// Round 16
// baseline (3545.376 us; speedup 1.0000x reference)
//
#include <hip/hip_runtime.h>
#include <hip/hip_bf16.h>

// GRU: SEQ=512, B=64, I=512, H=1024, O=512
#define SEQL 512
#define BATCH 64
#define INF 512
#define HID 1024
#define OUTF 512
#define SB (SEQL*BATCH)
#define BH (BATCH*HID)

typedef __attribute__((ext_vector_type(8))) __bf16 bf16x8;
typedef __attribute__((ext_vector_type(4))) float f32x4;
typedef __attribute__((ext_vector_type(8))) unsigned short us8;

__device__ inline bf16x8 ld_bf8(const void* p) { return *reinterpret_cast<const bf16x8*>(p); }
__device__ inline unsigned short f2bf(float f) { __bf16 b = (__bf16)f; return __builtin_bit_cast(unsigned short, b); }

// Coherent 8B store: relaxed agent-scope atomic -> write-through to IF, no cache maintenance.
__device__ inline void st_u64c(void* p, unsigned long long v) {
    __hip_atomic_store((unsigned long long*)p, v, __ATOMIC_RELAXED, __HIP_MEMORY_SCOPE_AGENT);
}

// ---------------- prep kernels ----------------
__global__ void cvt_f32_bf16(const float* __restrict__ src, unsigned short* __restrict__ dst, int n) {
    int i = (blockIdx.x * blockDim.x + threadIdx.x) * 4;
    if (i < n) {
        float4 v = *reinterpret_cast<const float4*>(src + i);
        ushort4 o = make_ushort4(f2bf(v.x), f2bf(v.y), f2bf(v.z), f2bf(v.w));
        *reinterpret_cast<ushort4*>(dst + i) = o;
    }
}

// x -> fragment-major bf16: xFM[(t*4+rb)<<13 + v*8], unit v = slot*16 + row holds
// x[t*64 + rb*16 + row][slot*8 .. +7]. One-time 33.5MB transpose.
__global__ void cvt_x_fm(const float* __restrict__ x, unsigned short* __restrict__ xFM) {
    int u = blockIdx.x * blockDim.x + threadIdx.x;   // 0 .. 2M-1
    int t = u >> 12, rb = (u >> 10) & 3, v = u & 1023;
    int row = v & 15, slot = v >> 4;
    const float* src = x + ((size_t)(t * 64 + rb * 16 + row) * INF + slot * 8);
    float4 a = *reinterpret_cast<const float4*>(src);
    float4 b = *reinterpret_cast<const float4*>(src + 4);
    us8 o = { f2bf(a.x), f2bf(a.y), f2bf(a.z), f2bf(a.w), f2bf(b.x), f2bf(b.y), f2bf(b.z), f2bf(b.w) };
    *reinterpret_cast<us8*>(xFM + (size_t)u * 8) = o;
}

__global__ void make_bias2(const float* bxz, const float* bhz, const float* bxr,
                           const float* bhr, float* bias2) {
    int i = blockIdx.x * blockDim.x + threadIdx.x;
    if (i < HID) bias2[i] = bxz[i] + bhz[i];
    else if (i < 2*HID) bias2[i] = bxr[i-HID] + bhr[i-HID];
}

__global__ void fail_sentinel(float* o) { o[0] = 1e9f; }

// ---------------- tiled NT GEMM; A read from the FRAGMENT-MAJOR hs layout (r15-validated) ----------------
__global__ __launch_bounds__(256, 2) void gemm_nt_f32(
        const unsigned short* __restrict__ A,     // hsFM + one t-block (t=1 start)
        const unsigned short* __restrict__ Bw, int ldb,
        const float* __restrict__ bias,
        float* __restrict__ Cf, int N, int K) {
    __shared__ __align__(16) char lds[32768];
    const int tid = threadIdx.x;
    const int ntn = N >> 7;
    const int bm = blockIdx.x / ntn, bn = blockIdx.x % ntn;
    const int rowbase = bm << 7, colbase = bn << 7;
    const int wave = tid >> 6, lane = tid & 63, lo = lane & 15, hi = lane >> 4;
    const int vm = wave >> 1, vn = wave & 1;

    auto stage = [&](int abase, int k0) {
        #pragma unroll
        for (int i = 0; i < 2; i++) {
            int linear = i * 256 + tid;
            int r = linear >> 2, s = linear & 3;
            int c = (s - (r >> 1)) & 3;
            int R = rowbase + r;
            const unsigned short* ga = A + ((size_t)(R >> 6) * 65536 + (size_t)((R >> 4) & 3) * 16384
                                     + (size_t)((((k0 + c * 8) >> 3) * 16) + (R & 15)) * 8);
            const unsigned short* gb = Bw + (size_t)(colbase + r) * ldb + k0 + c * 8;
            __builtin_amdgcn_global_load_lds(
                (const __attribute__((address_space(1))) unsigned int*)ga,
                (__attribute__((address_space(3))) unsigned int*)(lds + abase + linear * 16), 16, 0, 0);
            __builtin_amdgcn_global_load_lds(
                (const __attribute__((address_space(1))) unsigned int*)gb,
                (__attribute__((address_space(3))) unsigned int*)(lds + 16384 + abase + linear * 16), 16, 0, 0);
        }
    };

    f32x4 acc[4][4] = {};
    const int nk = K >> 5;
    stage(0, 0);
    for (int kt = 0; kt < nk; kt++) {
        __syncthreads();
        if (kt + 1 < nk) stage(((kt + 1) & 1) * 8192, (kt + 1) << 5);
        const char* cA = lds + (kt & 1) * 8192;
        const char* cB = lds + 16384 + (kt & 1) * 8192;
        bf16x8 af[4], bfr[4];
        #pragma unroll
        for (int m = 0; m < 4; m++) {
            int r = vm * 64 + m * 16 + lo;
            af[m] = ld_bf8(cA + r * 64 + 16 * ((hi + (r >> 1)) & 3));
        }
        #pragma unroll
        for (int n = 0; n < 4; n++) {
            int r = vn * 64 + n * 16 + lo;
            bfr[n] = ld_bf8(cB + r * 64 + 16 * ((hi + (r >> 1)) & 3));
        }
        #pragma unroll
        for (int m = 0; m < 4; m++)
            #pragma unroll
            for (int n = 0; n < 4; n++)
                acc[m][n] = __builtin_amdgcn_mfma_f32_16x16x32_bf16(af[m], bfr[n], acc[m][n], 0, 0, 0);
        __syncthreads();
    }

    #pragma unroll
    for (int n = 0; n < 4; n++) {
        int col = colbase + vn * 64 + n * 16 + lo;
        float bv = bias[col];
        #pragma unroll
        for (int m = 0; m < 4; m++)
            #pragma unroll
            for (int r = 0; r < 4; r++) {
                int row = rowbase + vm * 64 + m * 16 + hi * 4 + r;
                Cf[(size_t)row * N + col] = acc[m][n][r] + bv;
            }
    }
}

// ---------------- persistent GRU scan v12: r15 + LDS-staged x (tail = flag -> poll only) ----------------
// 256 WGs x 192 threads; rb = wid>>6 (16 batch rows, 4 independent scan groups), cb = wid&63.
// ROUND-15 POST-MORTEM: the tail x-prefetch (16 cold-HBM x loads + MFMAs) stalled the wave
// between flag-store and poll-A every step. NOW x[t+1] tiles stage through LDS (FM layout,
// precomputed by cvt_x_fm) alongside stage-h -- same coalesced global_load_lds, same barrier,
// no extra sync (x is read-only). x-MFMAs run right after consume-h (pure LDS). Tail = flag ->
// poll. Single x buffer is race-free: x-reads complete before the Px barrier; next write is
// after the next poll (Px barrier separates them).
// LDS: [0,96K) wh; [96K,128K) hstage; [128K,144K) xstage; then Px (3K) + T (512B) = 151040 B.
// All other machinery r11/r15-validated: split-half flags, cached stage loads, startup
// buffer_inv, producer T-repack -> one contiguous 8B store/lane -> vmcnt(0) -> flag store.
__global__ __launch_bounds__(192, 1) void gru_scan(
        const unsigned short* __restrict__ Whc,   // [3][H][H]
        const unsigned short* __restrict__ Wxc,   // [3][H][I]
        const unsigned short* __restrict__ xFM,   // [S][4 rb][1024 units][8]
        unsigned short* __restrict__ hsFM,        // [S+1][4 rb][2048 units][8]
        const float* __restrict__ bias2,          // [2H]
        const float* __restrict__ bxh,
        const float* __restrict__ bhh,
        unsigned int* flags) {                    // [4][64] per-WG step flags
    __shared__ __align__(16) char lds[151040];
    const int tid = threadIdx.x;
    const int wid = blockIdx.x;
    const int rb = wid >> 6;          // 0..3
    const int cb = wid & 63;
    const int g = tid / 64;
    const int lane = tid & 63, lo = lane & 15, hi = lane >> 4;
    const int col = cb * 16 + lo;
    char* whl = lds + g * 32768;                         // this wave's 32 wh frags
    char* hstage = lds + 98304;                          // 32 KB FM h tile
    char* xstage = lds + 131072;                         // 16 KB FM x tile
    f32x4* Px = (f32x4*)(lds + 147456);                  // 3 KB exchange
    unsigned short* T = (unsigned short*)(lds + 150528); // 512 B store-repack

    // ---- stage wh slices into LDS (once) ----
    {
        const unsigned short* ph = Whc + ((size_t)g * HID + col) * HID + hi * 8;
        #pragma unroll
        for (int kb = 0; kb < 32; kb++)
            __builtin_amdgcn_global_load_lds(
                (const __attribute__((address_space(1))) unsigned int*)(ph + kb * 32),
                (__attribute__((address_space(3))) unsigned int*)(whl + kb * 1024 + lane * 16), 16, 0, 0);
    }
    __syncthreads();
    asm volatile("buffer_inv sc0 sc1" ::: "memory");   // kill pre-launch hsFM L2 lines

    const float bzv  = bias2[col];
    const float brv  = bias2[HID + col];
    const float bxhv = bxh[col];
    const float bhhv = bhh[col];
    float hst[4] = {0.f, 0.f, 0.f, 0.f};   // fp32 state: row = rb*16 + hi*4 + r, col
    const unsigned short* wxp = Wxc + ((size_t)g * HID + col) * INF + hi * 8;
    const unsigned int* flA = flags + rb * 64 + (lane & 31);        // half-A producers (cb<32)
    const unsigned int* flB = flags + rb * 64 + 32 + (lane & 31);   // half-B producers

    // x-side preacts for t=0: direct reads from xFM (one-time, scattered OK)
    f32x4 ax = {0,0,0,0};
    {
        const unsigned short* xf0 = xFM + ((size_t)rb << 13);
        #pragma unroll
        for (int kb = 0; kb < 16; kb++) {
            bf16x8 a = ld_bf8(xf0 + (size_t)(((kb * 4 + hi) * 16) + lo) * 8);
            ax = __builtin_amdgcn_mfma_f32_16x16x32_bf16(a, ld_bf8(wxp + kb * 32), ax, 0, 0, 0);
        }
    }

    for (int t = 0; t < SEQL; t++) {
        // --- stage h[t] half A (poll-A passed at prev iter end) + stage x[t+1] (no sync needed) ---
        if (t > 0) {
            const unsigned short* hf = hsFM + (size_t)t * 65536 + rb * 16384;
            #pragma unroll
            for (int it = 0; it < 6; it++) {
                int v = it * 192 + tid;
                if (v < 1024)
                    __builtin_amdgcn_global_load_lds(
                        (const __attribute__((address_space(1))) unsigned int*)(hf + v * 8),
                        (__attribute__((address_space(3))) unsigned int*)(hstage + v * 16), 16, 0, 0);
            }
        }
        if (t + 1 < SEQL) {
            const unsigned short* xf = xFM + (((size_t)(t + 1) * 4 + rb) << 13);
            #pragma unroll
            for (int it = 0; it < 6; it++) {
                int v = it * 192 + tid;
                if (v < 1024)
                    __builtin_amdgcn_global_load_lds(
                        (const __attribute__((address_space(1))) unsigned int*)(xf + v * 8),
                        (__attribute__((address_space(3))) unsigned int*)(xstage + v * 16), 16, 0, 0);
            }
        }
        if (t > 0) {
            // --- poll half-B producers; A/x loads land under this RTT ---
            {
                unsigned int tgt = (unsigned int)t;
                while (!__all(__hip_atomic_load(flB, __ATOMIC_RELAXED, __HIP_MEMORY_SCOPE_AGENT) >= tgt))
                    __builtin_amdgcn_s_sleep(1);
                asm volatile("" ::: "memory");
            }
            const unsigned short* hf = hsFM + (size_t)t * 65536 + rb * 16384;
            #pragma unroll
            for (int it = 0; it < 6; it++) {
                int v = 1024 + it * 192 + tid;
                if (v < 2048)
                    __builtin_amdgcn_global_load_lds(
                        (const __attribute__((address_space(1))) unsigned int*)(hf + v * 8),
                        (__attribute__((address_space(3))) unsigned int*)(hstage + v * 16), 16, 0, 0);
            }
        }
        __syncthreads();   // h(t) + x(t+1) tiles landed

        // --- h-side preacts: conflict-free lane-linear LDS reads ---
        f32x4 ah = {0,0,0,0};
        if (t > 0) {
            #pragma unroll
            for (int kb = 0; kb < 32; kb++) {
                bf16x8 w = ld_bf8(whl + kb * 1024 + lane * 16);
                bf16x8 a = ld_bf8(hstage + kb * 1024 + lane * 16);
                ah = __builtin_amdgcn_mfma_f32_16x16x32_bf16(a, w, ah, 0, 0, 0);
            }
        }
        // --- x-side preacts for t+1 from LDS (no global stall; frees the tail) ---
        f32x4 nax = {0,0,0,0};
        if (t + 1 < SEQL) {
            #pragma unroll
            for (int kb = 0; kb < 16; kb++) {
                bf16x8 a = ld_bf8(xstage + kb * 1024 + lane * 16);
                nax = __builtin_amdgcn_mfma_f32_16x16x32_bf16(a, ld_bf8(wxp + kb * 32), nax, 0, 0, 0);
            }
        }

        // --- exchange r-pre and both hcand parts via LDS ---
        if (g == 1) {
            f32x4 v;
            #pragma unroll
            for (int r = 0; r < 4; r++) v[r] = ah[r] + ax[r] + brv;
            Px[0 * 64 + lane] = v;
        } else if (g == 2) {
            f32x4 v, w;
            #pragma unroll
            for (int r = 0; r < 4; r++) { v[r] = ah[r] + bhhv; w[r] = ax[r] + bxhv; }
            Px[1 * 64 + lane] = v;
            Px[2 * 64 + lane] = w;
        }
        __syncthreads();

        // --- finalize by wave 0: gates -> new h -> T-repack -> ONE contiguous 8B store/lane ---
        if (g == 0) {
            f32x4 pr = Px[0 * 64 + lane];
            f32x4 ph_ = Px[1 * 64 + lane];
            f32x4 px_ = Px[2 * 64 + lane];
            #pragma unroll
            for (int r = 0; r < 4; r++) {
                float z  = 1.f / (1.f + __expf(-(ah[r] + ax[r] + bzv)));
                float rr = 1.f / (1.f + __expf(-pr[r]));
                float hc = tanhf(px_[r] + rr * ph_[r]);
                hst[r] = (1.f - z) * hst[r] + z * hc;
                T[(hi * 4 + r) * 16 + lo] = f2bf(hst[r]);   // T[row16][col16]
            }
            asm volatile("s_waitcnt lgkmcnt(0)" ::: "memory");  // cross-lane T writes complete
            unsigned short* fmdst = hsFM + (size_t)(t + 1) * 65536 + rb * 16384 + cb * 256;
            st_u64c(fmdst + lane * 4,
                    *(const unsigned long long*)(T + ((lane >> 1) & 15) * 16 + (lane >> 5) * 8 + (lane & 1) * 4));
            asm volatile("s_waitcnt vmcnt(0)" ::: "memory");    // h-store at the IF
        }
        if (tid == 0)
            __hip_atomic_store(flags + rb * 64 + cb, (unsigned int)(t + 1),
                               __ATOMIC_RELAXED, __HIP_MEMORY_SCOPE_AGENT);

        // --- tail: poll half A only ---
        if (t + 1 < SEQL) {
            unsigned int tgt = (unsigned int)(t + 1);
            while (!__all(__hip_atomic_load(flA, __ATOMIC_RELAXED, __HIP_MEMORY_SCOPE_AGENT) >= tgt))
                __builtin_amdgcn_s_sleep(1);
            asm volatile("" ::: "memory");   // pin next iter's half-A stage behind the poll
        }
        ax = nax;
    }
}

// ---------------- host ----------------
extern "C" void kernel_launch(void* const* d_in, const int* in_sizes, int n_in,
                              void* d_out, int out_size, void* d_ws, size_t ws_size,
                              hipStream_t stream) {
    const float* x   = (const float*)d_in[0];
    const float* Wxz = (const float*)d_in[1];
    const float* bxz = (const float*)d_in[2];
    const float* Whz = (const float*)d_in[3];
    const float* bhz = (const float*)d_in[4];
    const float* Wxr = (const float*)d_in[5];
    const float* bxr = (const float*)d_in[6];
    const float* Whr = (const float*)d_in[7];
    const float* bhr = (const float*)d_in[8];
    const float* Wxh = (const float*)d_in[9];
    const float* bxh = (const float*)d_in[10];
    const float* Whh = (const float*)d_in[11];
    const float* bhh = (const float*)d_in[12];
    const float* Why = (const float*)d_in[13];
    const float* bhy = (const float*)d_in[14];

    char* ws = (char*)d_ws;
    size_t off = 0;
    auto alloc = [&](size_t bytes) { char* p = ws + off; off += (bytes + 255) & ~(size_t)255; return p; };
    unsigned short* Whc   = (unsigned short*)alloc((size_t)3 * HID * HID * 2);
    unsigned short* Wxc   = (unsigned short*)alloc((size_t)3 * HID * INF * 2);
    unsigned short* Whyb  = (unsigned short*)alloc((size_t)OUTF * HID * 2);
    float*          bias2 = (float*)alloc((size_t)2 * HID * 4);
    unsigned short* hsFM  = (unsigned short*)alloc((size_t)(SEQL + 1) * 65536 * 2); // 65.7 MB FM h
    unsigned int*   flags = (unsigned int*)alloc(1024);
    unsigned short* xFM   = (unsigned short*)d_out;  // 33.5 MB FM x; dead until the final GEMM

    if (off > ws_size) {
        fail_sentinel<<<dim3(1), dim3(1), 0, stream>>>((float*)d_out);
        return;
    }

    auto cvt = [&](const float* s, unsigned short* d, size_t n) {
        cvt_f32_bf16<<<dim3((unsigned)((n / 4 + 255) / 256)), dim3(256), 0, stream>>>(s, d, (int)n);
    };
    cvt_x_fm<<<dim3(8192), dim3(256), 0, stream>>>(x, xFM);
    cvt(Whz, Whc, (size_t)HID * HID);
    cvt(Whr, Whc + (size_t)HID * HID, (size_t)HID * HID);
    cvt(Whh, Whc + (size_t)2 * HID * HID, (size_t)HID * HID);
    cvt(Wxz, Wxc, (size_t)HID * INF);
    cvt(Wxr, Wxc + (size_t)HID * INF, (size_t)HID * INF);
    cvt(Wxh, Wxc + (size_t)2 * HID * INF, (size_t)HID * INF);
    cvt(Why, Whyb, (size_t)OUTF * HID);
    make_bias2<<<dim3(8), dim3(256), 0, stream>>>(bxz, bhz, bxr, bhr, bias2);
    (void)hipMemsetAsync(flags, 0, 1024, stream);   // reset per launch (graph-replay safe)

    gru_scan<<<dim3(256), dim3(192), 0, stream>>>(Whc, Wxc, xFM, hsFM, bias2, bxh, bhh, flags);

    // out[SB, O] = hs[1..512] @ Why^T + bhy ; A read from FM layout (t=1 block onward)
    gemm_nt_f32<<<dim3((SB / 128) * (OUTF / 128)), dim3(256), 0, stream>>>(
        hsFM + 65536, Whyb, HID, bhy, (float*)d_out, OUTF, HID);
}

// Round 17
// 3196.882 us; speedup vs baseline: 1.1090x; 1.1090x over previous
//
#include <hip/hip_runtime.h>
#include <hip/hip_bf16.h>

// GRU: SEQ=512, B=64, I=512, H=1024, O=512
#define SEQL 512
#define BATCH 64
#define INF 512
#define HID 1024
#define OUTF 512
#define SB (SEQL*BATCH)
#define BH (BATCH*HID)

typedef __attribute__((ext_vector_type(8))) __bf16 bf16x8;
typedef __attribute__((ext_vector_type(4))) float f32x4;

__device__ inline bf16x8 ld_bf8(const void* p) { return *reinterpret_cast<const bf16x8*>(p); }
__device__ inline unsigned short f2bf(float f) { __bf16 b = (__bf16)f; return __builtin_bit_cast(unsigned short, b); }

// Coherent 8B store: relaxed agent-scope atomic -> write-through to IF, no cache maintenance.
__device__ inline void st_u64c(void* p, unsigned long long v) {
    __hip_atomic_store((unsigned long long*)p, v, __ATOMIC_RELAXED, __HIP_MEMORY_SCOPE_AGENT);
}

// ---------------- prep kernels ----------------
__global__ void cvt_f32_bf16(const float* __restrict__ src, unsigned short* __restrict__ dst, int n) {
    int i = (blockIdx.x * blockDim.x + threadIdx.x) * 4;
    if (i < n) {
        float4 v = *reinterpret_cast<const float4*>(src + i);
        ushort4 o = make_ushort4(f2bf(v.x), f2bf(v.y), f2bf(v.z), f2bf(v.w));
        *reinterpret_cast<ushort4*>(dst + i) = o;
    }
}

__global__ void make_bias2(const float* bxz, const float* bhz, const float* bxr,
                           const float* bhr, float* bias2) {
    int i = blockIdx.x * blockDim.x + threadIdx.x;
    if (i < HID) bias2[i] = bxz[i] + bhz[i];
    else if (i < 2*HID) bias2[i] = bxr[i-HID] + bhr[i-HID];
}

__global__ void fail_sentinel(float* o) { o[0] = 1e9f; }

// ---------------- tiled NT GEMM; A read from the FRAGMENT-MAJOR hs layout (r15-validated) ----------------
__global__ __launch_bounds__(256, 2) void gemm_nt_f32(
        const unsigned short* __restrict__ A,     // hsFM + one t-block (t=1 start)
        const unsigned short* __restrict__ Bw, int ldb,
        const float* __restrict__ bias,
        float* __restrict__ Cf, int N, int K) {
    __shared__ __align__(16) char lds[32768];
    const int tid = threadIdx.x;
    const int ntn = N >> 7;
    const int bm = blockIdx.x / ntn, bn = blockIdx.x % ntn;
    const int rowbase = bm << 7, colbase = bn << 7;
    const int wave = tid >> 6, lane = tid & 63, lo = lane & 15, hi = lane >> 4;
    const int vm = wave >> 1, vn = wave & 1;

    auto stage = [&](int abase, int k0) {
        #pragma unroll
        for (int i = 0; i < 2; i++) {
            int linear = i * 256 + tid;
            int r = linear >> 2, s = linear & 3;
            int c = (s - (r >> 1)) & 3;
            int R = rowbase + r;
            const unsigned short* ga = A + ((size_t)(R >> 6) * 65536 + (size_t)((R >> 4) & 3) * 16384
                                     + (size_t)((((k0 + c * 8) >> 3) * 16) + (R & 15)) * 8);
            const unsigned short* gb = Bw + (size_t)(colbase + r) * ldb + k0 + c * 8;
            __builtin_amdgcn_global_load_lds(
                (const __attribute__((address_space(1))) unsigned int*)ga,
                (__attribute__((address_space(3))) unsigned int*)(lds + abase + linear * 16), 16, 0, 0);
            __builtin_amdgcn_global_load_lds(
                (const __attribute__((address_space(1))) unsigned int*)gb,
                (__attribute__((address_space(3))) unsigned int*)(lds + 16384 + abase + linear * 16), 16, 0, 0);
        }
    };

    f32x4 acc[4][4] = {};
    const int nk = K >> 5;
    stage(0, 0);
    for (int kt = 0; kt < nk; kt++) {
        __syncthreads();
        if (kt + 1 < nk) stage(((kt + 1) & 1) * 8192, (kt + 1) << 5);
        const char* cA = lds + (kt & 1) * 8192;
        const char* cB = lds + 16384 + (kt & 1) * 8192;
        bf16x8 af[4], bfr[4];
        #pragma unroll
        for (int m = 0; m < 4; m++) {
            int r = vm * 64 + m * 16 + lo;
            af[m] = ld_bf8(cA + r * 64 + 16 * ((hi + (r >> 1)) & 3));
        }
        #pragma unroll
        for (int n = 0; n < 4; n++) {
            int r = vn * 64 + n * 16 + lo;
            bfr[n] = ld_bf8(cB + r * 64 + 16 * ((hi + (r >> 1)) & 3));
        }
        #pragma unroll
        for (int m = 0; m < 4; m++)
            #pragma unroll
            for (int n = 0; n < 4; n++)
                acc[m][n] = __builtin_amdgcn_mfma_f32_16x16x32_bf16(af[m], bfr[n], acc[m][n], 0, 0, 0);
        __syncthreads();
    }

    #pragma unroll
    for (int n = 0; n < 4; n++) {
        int col = colbase + vn * 64 + n * 16 + lo;
        float bv = bias[col];
        #pragma unroll
        for (int m = 0; m < 4; m++)
            #pragma unroll
            for (int r = 0; r < 4; r++) {
                int row = rowbase + vm * 64 + m * 16 + hi * 4 + r;
                Cf[(size_t)row * N + col] = acc[m][n][r] + bv;
            }
    }
}

// ---------------- persistent GRU scan v13: r15 + counted-vmcnt two-phase consume (T3/T4) ----------------
// 256 WGs x 192 threads; rb = wid>>6 (16 batch rows, 4 independent scan groups), cb = wid&63.
// r15 base (2.86ms validated: FM h layout, coalesced cached stage, flag sync, T-repack store).
// ROUND-16 POST-MORTEM: __syncthreads' vmcnt(0) makes the stage drain all-or-nothing; the
// fix is HK's counted-vmcnt: issue ALL 16 stage loads (128 stager threads x 8+8, uniform
// count so the counted wait is per-thread-correct), then
//   s_waitcnt vmcnt(8) + raw s_barrier  -> half A in LDS; consume kb 0..15 while B lands
//   s_waitcnt vmcnt(0) + raw s_barrier  -> half B in LDS; consume kb 16..31
// sched_barrier(0) after each barrier pins the ds_reads (rule #18). Split-poll is obsolete:
// tail polls all 64 producer flags at once (one ballot load per wave).
// Race-freedom unchanged from r15: hstage WAR across iterations is separated by the Px
// __syncthreads; wave0's Px reads precede its next-iteration barrier arrivals.
__global__ __launch_bounds__(192, 1) void gru_scan(
        const unsigned short* __restrict__ Whc,   // [3][H][H]
        const unsigned short* __restrict__ Wxc,   // [3][H][I]
        const unsigned short* __restrict__ xbf,   // [S*B][I] row-major bf16
        unsigned short* __restrict__ hsFM,        // [S+1][4 rb][2048 units][8]
        const float* __restrict__ bias2,          // [2H]
        const float* __restrict__ bxh,
        const float* __restrict__ bhh,
        unsigned int* flags) {                    // [4][64] per-WG step flags
    __shared__ __align__(16) char lds[134656];
    const int tid = threadIdx.x;
    const int wid = blockIdx.x;
    const int rb = wid >> 6;          // 0..3
    const int cb = wid & 63;
    const int g = tid / 64;
    const int lane = tid & 63, lo = lane & 15, hi = lane >> 4;
    const int col = cb * 16 + lo;
    char* whl = lds + g * 32768;                         // this wave's 32 wh frags
    char* hstage = lds + 98304;                          // 32 KB FM h tile
    f32x4* Px = (f32x4*)(lds + 131072);                  // 3 KB exchange
    unsigned short* T = (unsigned short*)(lds + 134144); // 512 B store-repack

    // ---- stage wh slices into LDS (once) ----
    {
        const unsigned short* ph = Whc + ((size_t)g * HID + col) * HID + hi * 8;
        #pragma unroll
        for (int kb = 0; kb < 32; kb++)
            __builtin_amdgcn_global_load_lds(
                (const __attribute__((address_space(1))) unsigned int*)(ph + kb * 32),
                (__attribute__((address_space(3))) unsigned int*)(whl + kb * 1024 + lane * 16), 16, 0, 0);
    }
    __syncthreads();
    asm volatile("buffer_inv sc0 sc1" ::: "memory");   // kill pre-launch hsFM L2 lines

    const float bzv  = bias2[col];
    const float brv  = bias2[HID + col];
    const float bxhv = bxh[col];
    const float bhhv = bhh[col];
    float hst[4] = {0.f, 0.f, 0.f, 0.f};   // fp32 state: row = rb*16 + hi*4 + r, col
    const unsigned short* wxp = Wxc + ((size_t)g * HID + col) * INF + hi * 8;
    const unsigned int* pf = flags + rb * 64 + lane;     // all 64 producer flags

    // x-side preacts for t=0
    f32x4 ax = {0,0,0,0};
    {
        const unsigned short* xp = xbf + ((size_t)(rb * 16 + lo)) * INF + hi * 8;
        #pragma unroll
        for (int kb = 0; kb < 16; kb++)
            ax = __builtin_amdgcn_mfma_f32_16x16x32_bf16(ld_bf8(xp + kb * 32), ld_bf8(wxp + kb * 32), ax, 0, 0, 0);
    }

    for (int t = 0; t < SEQL; t++) {
        f32x4 ah = {0,0,0,0};
        if (t > 0) {
            // --- issue ALL stage loads: 128 stagers x (8 A-units + 8 B-units), uniform count ---
            const unsigned short* hf = hsFM + (size_t)t * 65536 + rb * 16384;
            if (tid < 128) {
                #pragma unroll
                for (int it = 0; it < 8; it++) {
                    int v = it * 128 + tid;           // half A: units 0..1023
                    __builtin_amdgcn_global_load_lds(
                        (const __attribute__((address_space(1))) unsigned int*)(hf + v * 8),
                        (__attribute__((address_space(3))) unsigned int*)(hstage + v * 16), 16, 0, 0);
                }
                #pragma unroll
                for (int it = 0; it < 8; it++) {
                    int v = 1024 + it * 128 + tid;    // half B: units 1024..2047
                    __builtin_amdgcn_global_load_lds(
                        (const __attribute__((address_space(1))) unsigned int*)(hf + v * 8),
                        (__attribute__((address_space(3))) unsigned int*)(hstage + v * 16), 16, 0, 0);
                }
            }
            // --- phase 1: half A landed (counted wait: oldest 8 = A) ---
            asm volatile("s_waitcnt vmcnt(8)" ::: "memory");
            __builtin_amdgcn_s_barrier();
            __builtin_amdgcn_sched_barrier(0);
            #pragma unroll
            for (int kb = 0; kb < 16; kb++) {         // consume A while B is in flight
                bf16x8 w = ld_bf8(whl + kb * 1024 + lane * 16);
                bf16x8 a = ld_bf8(hstage + kb * 1024 + lane * 16);
                ah = __builtin_amdgcn_mfma_f32_16x16x32_bf16(a, w, ah, 0, 0, 0);
            }
            // --- phase 2: half B landed ---
            asm volatile("s_waitcnt vmcnt(0)" ::: "memory");
            __builtin_amdgcn_s_barrier();
            __builtin_amdgcn_sched_barrier(0);
            #pragma unroll
            for (int kb = 16; kb < 32; kb++) {
                bf16x8 w = ld_bf8(whl + kb * 1024 + lane * 16);
                bf16x8 a = ld_bf8(hstage + kb * 1024 + lane * 16);
                ah = __builtin_amdgcn_mfma_f32_16x16x32_bf16(a, w, ah, 0, 0, 0);
            }
        }

        // --- exchange r-pre and both hcand parts via LDS ---
        if (g == 1) {
            f32x4 v;
            #pragma unroll
            for (int r = 0; r < 4; r++) v[r] = ah[r] + ax[r] + brv;
            Px[0 * 64 + lane] = v;
        } else if (g == 2) {
            f32x4 v, w;
            #pragma unroll
            for (int r = 0; r < 4; r++) { v[r] = ah[r] + bhhv; w[r] = ax[r] + bxhv; }
            Px[1 * 64 + lane] = v;
            Px[2 * 64 + lane] = w;
        }
        __syncthreads();

        // --- finalize by wave 0: gates -> new h -> T-repack -> ONE contiguous 8B store/lane ---
        if (g == 0) {
            f32x4 pr = Px[0 * 64 + lane];
            f32x4 ph_ = Px[1 * 64 + lane];
            f32x4 px_ = Px[2 * 64 + lane];
            #pragma unroll
            for (int r = 0; r < 4; r++) {
                float z  = 1.f / (1.f + __expf(-(ah[r] + ax[r] + bzv)));
                float rr = 1.f / (1.f + __expf(-pr[r]));
                float hc = tanhf(px_[r] + rr * ph_[r]);
                hst[r] = (1.f - z) * hst[r] + z * hc;
                T[(hi * 4 + r) * 16 + lo] = f2bf(hst[r]);   // T[row16][col16]
            }
            asm volatile("s_waitcnt lgkmcnt(0)" ::: "memory");  // cross-lane T writes complete
            unsigned short* fmdst = hsFM + (size_t)(t + 1) * 65536 + rb * 16384 + cb * 256;
            st_u64c(fmdst + lane * 4,
                    *(const unsigned long long*)(T + ((lane >> 1) & 15) * 16 + (lane >> 5) * 8 + (lane & 1) * 4));
            asm volatile("s_waitcnt vmcnt(0)" ::: "memory");    // h-store at the IF
        }
        if (tid == 0)
            __hip_atomic_store(flags + rb * 64 + cb, (unsigned int)(t + 1),
                               __ATOMIC_RELAXED, __HIP_MEMORY_SCOPE_AGENT);

        // --- tail: x-prefetch for t+1 (L2/HBM loads fly with the first poll read), poll ALL flags ---
        f32x4 nax = {0,0,0,0};
        if (t + 1 < SEQL) {
            const unsigned short* xp = xbf + ((size_t)(t + 1) * BATCH + rb * 16 + lo) * INF + hi * 8;
            #pragma unroll
            for (int kb = 0; kb < 16; kb++)
                nax = __builtin_amdgcn_mfma_f32_16x16x32_bf16(ld_bf8(xp + kb * 32), ld_bf8(wxp + kb * 32), nax, 0, 0, 0);
            unsigned int tgt = (unsigned int)(t + 1);
            while (!__all(__hip_atomic_load(pf, __ATOMIC_RELAXED, __HIP_MEMORY_SCOPE_AGENT) >= tgt))
                __builtin_amdgcn_s_sleep(1);
            asm volatile("" ::: "memory");   // pin next iter's stage behind the poll
        }
        ax = nax;
    }
}

// ---------------- host ----------------
extern "C" void kernel_launch(void* const* d_in, const int* in_sizes, int n_in,
                              void* d_out, int out_size, void* d_ws, size_t ws_size,
                              hipStream_t stream) {
    const float* x   = (const float*)d_in[0];
    const float* Wxz = (const float*)d_in[1];
    const float* bxz = (const float*)d_in[2];
    const float* Whz = (const float*)d_in[3];
    const float* bhz = (const float*)d_in[4];
    const float* Wxr = (const float*)d_in[5];
    const float* bxr = (const float*)d_in[6];
    const float* Whr = (const float*)d_in[7];
    const float* bhr = (const float*)d_in[8];
    const float* Wxh = (const float*)d_in[9];
    const float* bxh = (const float*)d_in[10];
    const float* Whh = (const float*)d_in[11];
    const float* bhh = (const float*)d_in[12];
    const float* Why = (const float*)d_in[13];
    const float* bhy = (const float*)d_in[14];

    char* ws = (char*)d_ws;
    size_t off = 0;
    auto alloc = [&](size_t bytes) { char* p = ws + off; off += (bytes + 255) & ~(size_t)255; return p; };
    unsigned short* Whc   = (unsigned short*)alloc((size_t)3 * HID * HID * 2);
    unsigned short* Wxc   = (unsigned short*)alloc((size_t)3 * HID * INF * 2);
    unsigned short* Whyb  = (unsigned short*)alloc((size_t)OUTF * HID * 2);
    float*          bias2 = (float*)alloc((size_t)2 * HID * 4);
    unsigned short* hsFM  = (unsigned short*)alloc((size_t)(SEQL + 1) * 65536 * 2); // 65.7 MB FM h
    unsigned int*   flags = (unsigned int*)alloc(1024);
    unsigned short* x_bf  = (unsigned short*)d_out;  // dead until the final GEMM

    if (off > ws_size) {
        fail_sentinel<<<dim3(1), dim3(1), 0, stream>>>((float*)d_out);
        return;
    }

    auto cvt = [&](const float* s, unsigned short* d, size_t n) {
        cvt_f32_bf16<<<dim3((unsigned)((n / 4 + 255) / 256)), dim3(256), 0, stream>>>(s, d, (int)n);
    };
    cvt(x, x_bf, (size_t)SB * INF);
    cvt(Whz, Whc, (size_t)HID * HID);
    cvt(Whr, Whc + (size_t)HID * HID, (size_t)HID * HID);
    cvt(Whh, Whc + (size_t)2 * HID * HID, (size_t)HID * HID);
    cvt(Wxz, Wxc, (size_t)HID * INF);
    cvt(Wxr, Wxc + (size_t)HID * INF, (size_t)HID * INF);
    cvt(Wxh, Wxc + (size_t)2 * HID * INF, (size_t)HID * INF);
    cvt(Why, Whyb, (size_t)OUTF * HID);
    make_bias2<<<dim3(8), dim3(256), 0, stream>>>(bxz, bhz, bxr, bhr, bias2);
    (void)hipMemsetAsync(flags, 0, 1024, stream);   // reset per launch (graph-replay safe)

    gru_scan<<<dim3(256), dim3(192), 0, stream>>>(Whc, Wxc, x_bf, hsFM, bias2, bxh, bhh, flags);

    // out[SB, O] = hs[1..512] @ Why^T + bhy ; A read from FM layout (t=1 block onward)
    gemm_nt_f32<<<dim3((SB / 128) * (OUTF / 128)), dim3(256), 0, stream>>>(
        hsFM + 65536, Whyb, HID, bhy, (float*)d_out, OUTF, HID);
}

// Round 18
// 2845.904 us; speedup vs baseline: 1.2458x; 1.1233x over previous
//
#include <hip/hip_runtime.h>
#include <hip/hip_bf16.h>

// GRU: SEQ=512, B=64, I=512, H=1024, O=512
#define SEQL 512
#define BATCH 64
#define INF 512
#define HID 1024
#define OUTF 512
#define SB (SEQL*BATCH)
#define BH (BATCH*HID)

typedef __attribute__((ext_vector_type(8))) __bf16 bf16x8;
typedef __attribute__((ext_vector_type(4))) float f32x4;

__device__ inline bf16x8 ld_bf8(const void* p) { return *reinterpret_cast<const bf16x8*>(p); }
__device__ inline unsigned short f2bf(float f) { __bf16 b = (__bf16)f; return __builtin_bit_cast(unsigned short, b); }

// Coherent 8B store: relaxed agent-scope atomic -> write-through to IF, no cache maintenance.
__device__ inline void st_u64c(void* p, unsigned long long v) {
    __hip_atomic_store((unsigned long long*)p, v, __ATOMIC_RELAXED, __HIP_MEMORY_SCOPE_AGENT);
}

// ---------------- prep kernels ----------------
__global__ void cvt_f32_bf16(const float* __restrict__ src, unsigned short* __restrict__ dst, int n) {
    int i = (blockIdx.x * blockDim.x + threadIdx.x) * 4;
    if (i < n) {
        float4 v = *reinterpret_cast<const float4*>(src + i);
        ushort4 o = make_ushort4(f2bf(v.x), f2bf(v.y), f2bf(v.z), f2bf(v.w));
        *reinterpret_cast<ushort4*>(dst + i) = o;
    }
}

__global__ void make_bias2(const float* bxz, const float* bhz, const float* bxr,
                           const float* bhr, float* bias2) {
    int i = blockIdx.x * blockDim.x + threadIdx.x;
    if (i < HID) bias2[i] = bxz[i] + bhz[i];
    else if (i < 2*HID) bias2[i] = bxr[i-HID] + bhr[i-HID];
}

__global__ void fail_sentinel(float* o) { o[0] = 1e9f; }

// ---------------- tiled NT GEMM; A read from the FRAGMENT-MAJOR hs layout (r15-validated) ----------------
__global__ __launch_bounds__(256, 2) void gemm_nt_f32(
        const unsigned short* __restrict__ A,     // hsFM + one t-block (t=1 start)
        const unsigned short* __restrict__ Bw, int ldb,
        const float* __restrict__ bias,
        float* __restrict__ Cf, int N, int K) {
    __shared__ __align__(16) char lds[32768];
    const int tid = threadIdx.x;
    const int ntn = N >> 7;
    const int bm = blockIdx.x / ntn, bn = blockIdx.x % ntn;
    const int rowbase = bm << 7, colbase = bn << 7;
    const int wave = tid >> 6, lane = tid & 63, lo = lane & 15, hi = lane >> 4;
    const int vm = wave >> 1, vn = wave & 1;

    auto stage = [&](int abase, int k0) {
        #pragma unroll
        for (int i = 0; i < 2; i++) {
            int linear = i * 256 + tid;
            int r = linear >> 2, s = linear & 3;
            int c = (s - (r >> 1)) & 3;
            int R = rowbase + r;
            const unsigned short* ga = A + ((size_t)(R >> 6) * 65536 + (size_t)((R >> 4) & 3) * 16384
                                     + (size_t)((((k0 + c * 8) >> 3) * 16) + (R & 15)) * 8);
            const unsigned short* gb = Bw + (size_t)(colbase + r) * ldb + k0 + c * 8;
            __builtin_amdgcn_global_load_lds(
                (const __attribute__((address_space(1))) unsigned int*)ga,
                (__attribute__((address_space(3))) unsigned int*)(lds + abase + linear * 16), 16, 0, 0);
            __builtin_amdgcn_global_load_lds(
                (const __attribute__((address_space(1))) unsigned int*)gb,
                (__attribute__((address_space(3))) unsigned int*)(lds + 16384 + abase + linear * 16), 16, 0, 0);
        }
    };

    f32x4 acc[4][4] = {};
    const int nk = K >> 5;
    stage(0, 0);
    for (int kt = 0; kt < nk; kt++) {
        __syncthreads();
        if (kt + 1 < nk) stage(((kt + 1) & 1) * 8192, (kt + 1) << 5);
        const char* cA = lds + (kt & 1) * 8192;
        const char* cB = lds + 16384 + (kt & 1) * 8192;
        bf16x8 af[4], bfr[4];
        #pragma unroll
        for (int m = 0; m < 4; m++) {
            int r = vm * 64 + m * 16 + lo;
            af[m] = ld_bf8(cA + r * 64 + 16 * ((hi + (r >> 1)) & 3));
        }
        #pragma unroll
        for (int n = 0; n < 4; n++) {
            int r = vn * 64 + n * 16 + lo;
            bfr[n] = ld_bf8(cB + r * 64 + 16 * ((hi + (r >> 1)) & 3));
        }
        #pragma unroll
        for (int m = 0; m < 4; m++)
            #pragma unroll
            for (int n = 0; n < 4; n++)
                acc[m][n] = __builtin_amdgcn_mfma_f32_16x16x32_bf16(af[m], bfr[n], acc[m][n], 0, 0, 0);
        __syncthreads();
    }

    #pragma unroll
    for (int n = 0; n < 4; n++) {
        int col = colbase + vn * 64 + n * 16 + lo;
        float bv = bias[col];
        #pragma unroll
        for (int m = 0; m < 4; m++)
            #pragma unroll
            for (int r = 0; r < 4; r++) {
                int row = rowbase + vm * 64 + m * 16 + hi * 4 + r;
                Cf[(size_t)row * N + col] = acc[m][n][r] + bv;
            }
    }
}

// ---------------- persistent GRU scan v14: r15 + IF-direct (bypass) stage loads ----------------
// EXACTLY r15 (2857us validated: FM h layout, coalesced stage, split-half flags, T-repack
// producer store, tail x-prefetch) with ONE variable changed: the h-stage global_load_lds
// uses aux=17 (SC0|SC1, served directly at the Infinity Cache coherence point) instead of
// cached. Rationale: r11 chose cached when stage addresses were 16B-scattered (L2 dedup cut
// 8x transactions). With r15's FM coalescing that argument is moot, and the L2-miss->IF->
// fill->serve hop on every first touch is pure critical-path latency. r10's bypass failure
// was transaction count (524K scattered), not bypass itself; FM = 256x128B transactions/WG.
// A/B: faster => L2 hop was on the chain; ~equal => neutral; slower => cross-WG L2 dedup
// still mattered (16 same-XCD WGs share lines) -> revert and declare plateau.
__global__ __launch_bounds__(192, 1) void gru_scan(
        const unsigned short* __restrict__ Whc,   // [3][H][H]
        const unsigned short* __restrict__ Wxc,   // [3][H][I]
        const unsigned short* __restrict__ xbf,   // [S*B][I] row-major bf16
        unsigned short* __restrict__ hsFM,        // [S+1][4 rb][2048 units][8]
        const float* __restrict__ bias2,          // [2H]
        const float* __restrict__ bxh,
        const float* __restrict__ bhh,
        unsigned int* flags) {                    // [4][64] per-WG step flags
    __shared__ __align__(16) char lds[134656];
    const int tid = threadIdx.x;
    const int wid = blockIdx.x;
    const int rb = wid >> 6;          // 0..3
    const int cb = wid & 63;
    const int g = tid / 64;
    const int lane = tid & 63, lo = lane & 15, hi = lane >> 4;
    const int col = cb * 16 + lo;
    char* whl = lds + g * 32768;                         // this wave's 32 wh frags
    char* hstage = lds + 98304;                          // 32 KB FM h tile
    f32x4* Px = (f32x4*)(lds + 131072);                  // 3 KB exchange
    unsigned short* T = (unsigned short*)(lds + 134144); // 512 B store-repack

    // ---- stage wh slices into LDS (once) ----
    {
        const unsigned short* ph = Whc + ((size_t)g * HID + col) * HID + hi * 8;
        #pragma unroll
        for (int kb = 0; kb < 32; kb++)
            __builtin_amdgcn_global_load_lds(
                (const __attribute__((address_space(1))) unsigned int*)(ph + kb * 32),
                (__attribute__((address_space(3))) unsigned int*)(whl + kb * 1024 + lane * 16), 16, 0, 0);
    }
    __syncthreads();
    asm volatile("buffer_inv sc0 sc1" ::: "memory");   // kill pre-launch L2 lines (safety)

    const float bzv  = bias2[col];
    const float brv  = bias2[HID + col];
    const float bxhv = bxh[col];
    const float bhhv = bhh[col];
    float hst[4] = {0.f, 0.f, 0.f, 0.f};   // fp32 state: row = rb*16 + hi*4 + r, col
    const unsigned short* wxp = Wxc + ((size_t)g * HID + col) * INF + hi * 8;
    const unsigned int* flA = flags + rb * 64 + (lane & 31);        // half-A producers (cb<32)
    const unsigned int* flB = flags + rb * 64 + 32 + (lane & 31);   // half-B producers

    // x-side preacts for t=0
    f32x4 ax = {0,0,0,0};
    {
        const unsigned short* xp = xbf + ((size_t)(rb * 16 + lo)) * INF + hi * 8;
        #pragma unroll
        for (int kb = 0; kb < 16; kb++)
            ax = __builtin_amdgcn_mfma_f32_16x16x32_bf16(ld_bf8(xp + kb * 32), ld_bf8(wxp + kb * 32), ax, 0, 0, 0);
    }

    for (int t = 0; t < SEQL; t++) {
        // --- stage h[t] from FM layout: coalesced, IF-direct (poll-A at prev iter end) ---
        if (t > 0) {
            const unsigned short* hf = hsFM + (size_t)t * 65536 + rb * 16384;
            #pragma unroll
            for (int it = 0; it < 6; it++) {            // half A: units 0..1023 (k < 512)
                int v = it * 192 + tid;
                if (v < 1024)
                    __builtin_amdgcn_global_load_lds(
                        (const __attribute__((address_space(1))) unsigned int*)(hf + v * 8),
                        (__attribute__((address_space(3))) unsigned int*)(hstage + v * 16), 16, 0, 17 /*SC0|SC1*/);
            }
            // --- poll half-B producers; A-loads land under this RTT ---
            {
                unsigned int tgt = (unsigned int)t;
                while (!__all(__hip_atomic_load(flB, __ATOMIC_RELAXED, __HIP_MEMORY_SCOPE_AGENT) >= tgt))
                    __builtin_amdgcn_s_sleep(1);
                asm volatile("" ::: "memory");
            }
            #pragma unroll
            for (int it = 0; it < 6; it++) {            // half B: units 1024..2047
                int v = 1024 + it * 192 + tid;
                if (v < 2048)
                    __builtin_amdgcn_global_load_lds(
                        (const __attribute__((address_space(1))) unsigned int*)(hf + v * 8),
                        (__attribute__((address_space(3))) unsigned int*)(hstage + v * 16), 16, 0, 17);
            }
        }
        __syncthreads();   // stage landed (per-thread vmcnt drained at barrier)

        // --- h-side preacts: conflict-free lane-linear LDS reads (r11/r15-identical) ---
        f32x4 ah = {0,0,0,0};
        if (t > 0) {
            #pragma unroll
            for (int kb = 0; kb < 32; kb++) {
                bf16x8 w = ld_bf8(whl + kb * 1024 + lane * 16);
                bf16x8 a = ld_bf8(hstage + kb * 1024 + lane * 16);
                ah = __builtin_amdgcn_mfma_f32_16x16x32_bf16(a, w, ah, 0, 0, 0);
            }
        }

        // --- exchange r-pre and both hcand parts via LDS ---
        if (g == 1) {
            f32x4 v;
            #pragma unroll
            for (int r = 0; r < 4; r++) v[r] = ah[r] + ax[r] + brv;
            Px[0 * 64 + lane] = v;
        } else if (g == 2) {
            f32x4 v, w;
            #pragma unroll
            for (int r = 0; r < 4; r++) { v[r] = ah[r] + bhhv; w[r] = ax[r] + bxhv; }
            Px[1 * 64 + lane] = v;
            Px[2 * 64 + lane] = w;
        }
        __syncthreads();

        // --- finalize by wave 0: gates -> new h -> T-repack -> ONE contiguous 8B store/lane ---
        if (g == 0) {
            f32x4 pr = Px[0 * 64 + lane];
            f32x4 ph_ = Px[1 * 64 + lane];
            f32x4 px_ = Px[2 * 64 + lane];
            #pragma unroll
            for (int r = 0; r < 4; r++) {
                float z  = 1.f / (1.f + __expf(-(ah[r] + ax[r] + bzv)));
                float rr = 1.f / (1.f + __expf(-pr[r]));
                float hc = tanhf(px_[r] + rr * ph_[r]);
                hst[r] = (1.f - z) * hst[r] + z * hc;
                T[(hi * 4 + r) * 16 + lo] = f2bf(hst[r]);   // T[row16][col16]
            }
            asm volatile("s_waitcnt lgkmcnt(0)" ::: "memory");  // cross-lane T writes complete
            unsigned short* fmdst = hsFM + (size_t)(t + 1) * 65536 + rb * 16384 + cb * 256;
            st_u64c(fmdst + lane * 4,
                    *(const unsigned long long*)(T + ((lane >> 1) & 15) * 16 + (lane >> 5) * 8 + (lane & 1) * 4));
            asm volatile("s_waitcnt vmcnt(0)" ::: "memory");    // h-store at the IF
        }
        if (tid == 0)
            __hip_atomic_store(flags + rb * 64 + cb, (unsigned int)(t + 1),
                               __ATOMIC_RELAXED, __HIP_MEMORY_SCOPE_AGENT);

        // --- x-prefetch for t+1 (L2-warm) overlaps flag propagation; then poll half A ---
        f32x4 nax = {0,0,0,0};
        if (t + 1 < SEQL) {
            const unsigned short* xp = xbf + ((size_t)(t + 1) * BATCH + rb * 16 + lo) * INF + hi * 8;
            #pragma unroll
            for (int kb = 0; kb < 16; kb++)
                nax = __builtin_amdgcn_mfma_f32_16x16x32_bf16(ld_bf8(xp + kb * 32), ld_bf8(wxp + kb * 32), nax, 0, 0, 0);
            unsigned int tgt = (unsigned int)(t + 1);
            while (!__all(__hip_atomic_load(flA, __ATOMIC_RELAXED, __HIP_MEMORY_SCOPE_AGENT) >= tgt))
                __builtin_amdgcn_s_sleep(1);
            asm volatile("" ::: "memory");   // pin next iter's half-A stage behind the poll
        }
        ax = nax;
    }
}

// ---------------- host ----------------
extern "C" void kernel_launch(void* const* d_in, const int* in_sizes, int n_in,
                              void* d_out, int out_size, void* d_ws, size_t ws_size,
                              hipStream_t stream) {
    const float* x   = (const float*)d_in[0];
    const float* Wxz = (const float*)d_in[1];
    const float* bxz = (const float*)d_in[2];
    const float* Whz = (const float*)d_in[3];
    const float* bhz = (const float*)d_in[4];
    const float* Wxr = (const float*)d_in[5];
    const float* bxr = (const float*)d_in[6];
    const float* Whr = (const float*)d_in[7];
    const float* bhr = (const float*)d_in[8];
    const float* Wxh = (const float*)d_in[9];
    const float* bxh = (const float*)d_in[10];
    const float* Whh = (const float*)d_in[11];
    const float* bhh = (const float*)d_in[12];
    const float* Why = (const float*)d_in[13];
    const float* bhy = (const float*)d_in[14];

    char* ws = (char*)d_ws;
    size_t off = 0;
    auto alloc = [&](size_t bytes) { char* p = ws + off; off += (bytes + 255) & ~(size_t)255; return p; };
    unsigned short* Whc   = (unsigned short*)alloc((size_t)3 * HID * HID * 2);
    unsigned short* Wxc   = (unsigned short*)alloc((size_t)3 * HID * INF * 2);
    unsigned short* Whyb  = (unsigned short*)alloc((size_t)OUTF * HID * 2);
    float*          bias2 = (float*)alloc((size_t)2 * HID * 4);
    unsigned short* hsFM  = (unsigned short*)alloc((size_t)(SEQL + 1) * 65536 * 2); // 65.7 MB FM h
    unsigned int*   flags = (unsigned int*)alloc(1024);
    unsigned short* x_bf  = (unsigned short*)d_out;  // dead until the final GEMM

    if (off > ws_size) {
        fail_sentinel<<<dim3(1), dim3(1), 0, stream>>>((float*)d_out);
        return;
    }

    auto cvt = [&](const float* s, unsigned short* d, size_t n) {
        cvt_f32_bf16<<<dim3((unsigned)((n / 4 + 255) / 256)), dim3(256), 0, stream>>>(s, d, (int)n);
    };
    cvt(x, x_bf, (size_t)SB * INF);
    cvt(Whz, Whc, (size_t)HID * HID);
    cvt(Whr, Whc + (size_t)HID * HID, (size_t)HID * HID);
    cvt(Whh, Whc + (size_t)2 * HID * HID, (size_t)HID * HID);
    cvt(Wxz, Wxc, (size_t)HID * INF);
    cvt(Wxr, Wxc + (size_t)HID * INF, (size_t)HID * INF);
    cvt(Wxh, Wxc + (size_t)2 * HID * INF, (size_t)HID * INF);
    cvt(Why, Whyb, (size_t)OUTF * HID);
    make_bias2<<<dim3(8), dim3(256), 0, stream>>>(bxz, bhz, bxr, bhr, bias2);
    (void)hipMemsetAsync(flags, 0, 1024, stream);   // reset per launch (graph-replay safe)

    gru_scan<<<dim3(256), dim3(192), 0, stream>>>(Whc, Wxc, x_bf, hsFM, bias2, bxh, bhh, flags);

    // out[SB, O] = hs[1..512] @ Why^T + bhy ; A read from FM layout (t=1 block onward)
    gemm_nt_f32<<<dim3((SB / 128) * (OUTF / 128)), dim3(256), 0, stream>>>(
        hsFM + 65536, Whyb, HID, bhy, (float*)d_out, OUTF, HID);
}

// Round 19
// 2463.049 us; speedup vs baseline: 1.4394x; 1.1554x over previous
//
#include <hip/hip_runtime.h>
#include <hip/hip_bf16.h>

// GRU: SEQ=512, B=64, I=512, H=1024, O=512
#define SEQL 512
#define BATCH 64
#define INF 512
#define HID 1024
#define OUTF 512
#define SB (SEQL*BATCH)
#define BH (BATCH*HID)

typedef __attribute__((ext_vector_type(8))) __bf16 bf16x8;
typedef __attribute__((ext_vector_type(4))) float f32x4;

__device__ inline bf16x8 ld_bf8(const void* p) { return *reinterpret_cast<const bf16x8*>(p); }
__device__ inline unsigned short f2bf(float f) { __bf16 b = (__bf16)f; return __builtin_bit_cast(unsigned short, b); }

// Coherent 8B store: relaxed agent-scope atomic -> write-through to IF, no cache maintenance.
__device__ inline void st_u64c(void* p, unsigned long long v) {
    __hip_atomic_store((unsigned long long*)p, v, __ATOMIC_RELAXED, __HIP_MEMORY_SCOPE_AGENT);
}

// ---------------- prep kernels ----------------
__global__ void cvt_f32_bf16(const float* __restrict__ src, unsigned short* __restrict__ dst, int n) {
    int i = (blockIdx.x * blockDim.x + threadIdx.x) * 4;
    if (i < n) {
        float4 v = *reinterpret_cast<const float4*>(src + i);
        ushort4 o = make_ushort4(f2bf(v.x), f2bf(v.y), f2bf(v.z), f2bf(v.w));
        *reinterpret_cast<ushort4*>(dst + i) = o;
    }
}

__global__ void make_bias2(const float* bxz, const float* bhz, const float* bxr,
                           const float* bhr, float* bias2) {
    int i = blockIdx.x * blockDim.x + threadIdx.x;
    if (i < HID) bias2[i] = bxz[i] + bhz[i];
    else if (i < 2*HID) bias2[i] = bxr[i-HID] + bhr[i-HID];
}

__global__ void fail_sentinel(float* o) { o[0] = 1e9f; }

// ---------------- tiled NT GEMM; A read from the FRAGMENT-MAJOR hs layout (r15-validated) ----------------
__global__ __launch_bounds__(256, 2) void gemm_nt_f32(
        const unsigned short* __restrict__ A,     // hsFM + one t-block (t=1 start)
        const unsigned short* __restrict__ Bw, int ldb,
        const float* __restrict__ bias,
        float* __restrict__ Cf, int N, int K) {
    __shared__ __align__(16) char lds[32768];
    const int tid = threadIdx.x;
    const int ntn = N >> 7;
    const int bm = blockIdx.x / ntn, bn = blockIdx.x % ntn;
    const int rowbase = bm << 7, colbase = bn << 7;
    const int wave = tid >> 6, lane = tid & 63, lo = lane & 15, hi = lane >> 4;
    const int vm = wave >> 1, vn = wave & 1;

    auto stage = [&](int abase, int k0) {
        #pragma unroll
        for (int i = 0; i < 2; i++) {
            int linear = i * 256 + tid;
            int r = linear >> 2, s = linear & 3;
            int c = (s - (r >> 1)) & 3;
            int R = rowbase + r;
            const unsigned short* ga = A + ((size_t)(R >> 6) * 65536 + (size_t)((R >> 4) & 3) * 16384
                                     + (size_t)((((k0 + c * 8) >> 3) * 16) + (R & 15)) * 8);
            const unsigned short* gb = Bw + (size_t)(colbase + r) * ldb + k0 + c * 8;
            __builtin_amdgcn_global_load_lds(
                (const __attribute__((address_space(1))) unsigned int*)ga,
                (__attribute__((address_space(3))) unsigned int*)(lds + abase + linear * 16), 16, 0, 0);
            __builtin_amdgcn_global_load_lds(
                (const __attribute__((address_space(1))) unsigned int*)gb,
                (__attribute__((address_space(3))) unsigned int*)(lds + 16384 + abase + linear * 16), 16, 0, 0);
        }
    };

    f32x4 acc[4][4] = {};
    const int nk = K >> 5;
    stage(0, 0);
    for (int kt = 0; kt < nk; kt++) {
        __syncthreads();
        if (kt + 1 < nk) stage(((kt + 1) & 1) * 8192, (kt + 1) << 5);
        const char* cA = lds + (kt & 1) * 8192;
        const char* cB = lds + 16384 + (kt & 1) * 8192;
        bf16x8 af[4], bfr[4];
        #pragma unroll
        for (int m = 0; m < 4; m++) {
            int r = vm * 64 + m * 16 + lo;
            af[m] = ld_bf8(cA + r * 64 + 16 * ((hi + (r >> 1)) & 3));
        }
        #pragma unroll
        for (int n = 0; n < 4; n++) {
            int r = vn * 64 + n * 16 + lo;
            bfr[n] = ld_bf8(cB + r * 64 + 16 * ((hi + (r >> 1)) & 3));
        }
        #pragma unroll
        for (int m = 0; m < 4; m++)
            #pragma unroll
            for (int n = 0; n < 4; n++)
                acc[m][n] = __builtin_amdgcn_mfma_f32_16x16x32_bf16(af[m], bfr[n], acc[m][n], 0, 0, 0);
        __syncthreads();
    }

    #pragma unroll
    for (int n = 0; n < 4; n++) {
        int col = colbase + vn * 64 + n * 16 + lo;
        float bv = bias[col];
        #pragma unroll
        for (int m = 0; m < 4; m++)
            #pragma unroll
            for (int r = 0; r < 4; r++) {
                int row = rowbase + vm * 64 + m * 16 + hi * 4 + r;
                Cf[(size_t)row * N + col] = acc[m][n][r] + bv;
            }
    }
}

// ---------------- persistent GRU scan v15: r18 + single-poller flag election (contention fix) ----------------
// EXACTLY r18 (2846us best: FM h layout, coalesced IF-direct stage, split-half flags,
// T-repack producer store, tail x-prefetch) with ONE variable changed: flag polling.
// ROUND-18 NULL closed the data-path hypotheses; remaining mechanism is READ CONTENTION ON
// THE FLAG LINE: 192 waves/group polling the same 1-2 IF lines every ~0.7us (~270 reads/us)
// that 64 producers must WRITE -- store service/visibility delayed by arbitration, invisible
// to all PMC counters (pure idle time). Fix: per WG only wave 1 (lightest) polls globally;
// it publishes a monotonic LDS counter go = 2t+1 (half-B ready for step t) / 2t+2 (half-A
// ready for t+1); waves 0,2 spin on LDS (intra-CU, no IF traffic, ~50ns detect). 3x less
// read pressure on the flag lines. Ordering: each wave's stage loads stay pinned behind its
// gate (loop dependence + asm memory); barriers unchanged; monotonic counter needs no reset.
__global__ __launch_bounds__(192, 1) void gru_scan(
        const unsigned short* __restrict__ Whc,   // [3][H][H]
        const unsigned short* __restrict__ Wxc,   // [3][H][I]
        const unsigned short* __restrict__ xbf,   // [S*B][I] row-major bf16
        unsigned short* __restrict__ hsFM,        // [S+1][4 rb][2048 units][8]
        const float* __restrict__ bias2,          // [2H]
        const float* __restrict__ bxh,
        const float* __restrict__ bhh,
        unsigned int* flags) {                    // [4][64] per-WG step flags
    __shared__ __align__(16) char lds[134720];
    const int tid = threadIdx.x;
    const int wid = blockIdx.x;
    const int rb = wid >> 6;          // 0..3
    const int cb = wid & 63;
    const int g = tid / 64;
    const int lane = tid & 63, lo = lane & 15, hi = lane >> 4;
    const int col = cb * 16 + lo;
    char* whl = lds + g * 32768;                         // this wave's 32 wh frags
    char* hstage = lds + 98304;                          // 32 KB FM h tile
    f32x4* Px = (f32x4*)(lds + 131072);                  // 3 KB exchange
    unsigned short* T = (unsigned short*)(lds + 134144); // 512 B store-repack
    unsigned int* go = (unsigned int*)(lds + 134656);    // monotonic poller-election word

    // ---- stage wh slices into LDS (once); init go ----
    {
        const unsigned short* ph = Whc + ((size_t)g * HID + col) * HID + hi * 8;
        #pragma unroll
        for (int kb = 0; kb < 32; kb++)
            __builtin_amdgcn_global_load_lds(
                (const __attribute__((address_space(1))) unsigned int*)(ph + kb * 32),
                (__attribute__((address_space(3))) unsigned int*)(whl + kb * 1024 + lane * 16), 16, 0, 0);
    }
    if (tid == 0) *go = 0u;
    __syncthreads();
    asm volatile("buffer_inv sc0 sc1" ::: "memory");   // kill pre-launch L2 lines (safety)

    const float bzv  = bias2[col];
    const float brv  = bias2[HID + col];
    const float bxhv = bxh[col];
    const float bhhv = bhh[col];
    float hst[4] = {0.f, 0.f, 0.f, 0.f};   // fp32 state: row = rb*16 + hi*4 + r, col
    const unsigned short* wxp = Wxc + ((size_t)g * HID + col) * INF + hi * 8;
    const unsigned int* flA = flags + rb * 64 + (lane & 31);        // half-A producers (cb<32)
    const unsigned int* flB = flags + rb * 64 + 32 + (lane & 31);   // half-B producers

    // x-side preacts for t=0
    f32x4 ax = {0,0,0,0};
    {
        const unsigned short* xp = xbf + ((size_t)(rb * 16 + lo)) * INF + hi * 8;
        #pragma unroll
        for (int kb = 0; kb < 16; kb++)
            ax = __builtin_amdgcn_mfma_f32_16x16x32_bf16(ld_bf8(xp + kb * 32), ld_bf8(wxp + kb * 32), ax, 0, 0, 0);
    }

    for (int t = 0; t < SEQL; t++) {
        // --- stage h[t] half A (gated last iter), then B-gate, then half B ---
        if (t > 0) {
            const unsigned short* hf = hsFM + (size_t)t * 65536 + rb * 16384;
            #pragma unroll
            for (int it = 0; it < 6; it++) {            // half A: units 0..1023 (k < 512)
                int v = it * 192 + tid;
                if (v < 1024)
                    __builtin_amdgcn_global_load_lds(
                        (const __attribute__((address_space(1))) unsigned int*)(hf + v * 8),
                        (__attribute__((address_space(3))) unsigned int*)(hstage + v * 16), 16, 0, 17 /*SC0|SC1*/);
            }
            // --- half-B gate: wave 1 polls globally, others spin on LDS (A-loads fly meanwhile) ---
            if (g == 1) {
                unsigned int tgt = (unsigned int)t;
                while (!__all(__hip_atomic_load(flB, __ATOMIC_RELAXED, __HIP_MEMORY_SCOPE_AGENT) >= tgt))
                    __builtin_amdgcn_s_sleep(1);
                __hip_atomic_store(go, 2u * (unsigned)t + 1u, __ATOMIC_RELAXED, __HIP_MEMORY_SCOPE_WORKGROUP);
            } else {
                unsigned int tgtg = 2u * (unsigned)t + 1u;
                while (__hip_atomic_load(go, __ATOMIC_RELAXED, __HIP_MEMORY_SCOPE_WORKGROUP) < tgtg)
                    __builtin_amdgcn_s_sleep(1);
            }
            asm volatile("" ::: "memory");
            #pragma unroll
            for (int it = 0; it < 6; it++) {            // half B: units 1024..2047
                int v = 1024 + it * 192 + tid;
                if (v < 2048)
                    __builtin_amdgcn_global_load_lds(
                        (const __attribute__((address_space(1))) unsigned int*)(hf + v * 8),
                        (__attribute__((address_space(3))) unsigned int*)(hstage + v * 16), 16, 0, 17);
            }
        }
        __syncthreads();   // stage landed (per-thread vmcnt drained at barrier)

        // --- h-side preacts: conflict-free lane-linear LDS reads (r11/r15-identical) ---
        f32x4 ah = {0,0,0,0};
        if (t > 0) {
            #pragma unroll
            for (int kb = 0; kb < 32; kb++) {
                bf16x8 w = ld_bf8(whl + kb * 1024 + lane * 16);
                bf16x8 a = ld_bf8(hstage + kb * 1024 + lane * 16);
                ah = __builtin_amdgcn_mfma_f32_16x16x32_bf16(a, w, ah, 0, 0, 0);
            }
        }

        // --- exchange r-pre and both hcand parts via LDS ---
        if (g == 1) {
            f32x4 v;
            #pragma unroll
            for (int r = 0; r < 4; r++) v[r] = ah[r] + ax[r] + brv;
            Px[0 * 64 + lane] = v;
        } else if (g == 2) {
            f32x4 v, w;
            #pragma unroll
            for (int r = 0; r < 4; r++) { v[r] = ah[r] + bhhv; w[r] = ax[r] + bxhv; }
            Px[1 * 64 + lane] = v;
            Px[2 * 64 + lane] = w;
        }
        __syncthreads();

        // --- finalize by wave 0: gates -> new h -> T-repack -> ONE contiguous 8B store/lane ---
        if (g == 0) {
            f32x4 pr = Px[0 * 64 + lane];
            f32x4 ph_ = Px[1 * 64 + lane];
            f32x4 px_ = Px[2 * 64 + lane];
            #pragma unroll
            for (int r = 0; r < 4; r++) {
                float z  = 1.f / (1.f + __expf(-(ah[r] + ax[r] + bzv)));
                float rr = 1.f / (1.f + __expf(-pr[r]));
                float hc = tanhf(px_[r] + rr * ph_[r]);
                hst[r] = (1.f - z) * hst[r] + z * hc;
                T[(hi * 4 + r) * 16 + lo] = f2bf(hst[r]);   // T[row16][col16]
            }
            asm volatile("s_waitcnt lgkmcnt(0)" ::: "memory");  // cross-lane T writes complete
            unsigned short* fmdst = hsFM + (size_t)(t + 1) * 65536 + rb * 16384 + cb * 256;
            st_u64c(fmdst + lane * 4,
                    *(const unsigned long long*)(T + ((lane >> 1) & 15) * 16 + (lane >> 5) * 8 + (lane & 1) * 4));
            asm volatile("s_waitcnt vmcnt(0)" ::: "memory");    // h-store at the IF
        }
        if (tid == 0)
            __hip_atomic_store(flags + rb * 64 + cb, (unsigned int)(t + 1),
                               __ATOMIC_RELAXED, __HIP_MEMORY_SCOPE_AGENT);

        // --- tail: x-prefetch for t+1, then half-A gate (wave 1 polls, others spin LDS) ---
        f32x4 nax = {0,0,0,0};
        if (t + 1 < SEQL) {
            const unsigned short* xp = xbf + ((size_t)(t + 1) * BATCH + rb * 16 + lo) * INF + hi * 8;
            #pragma unroll
            for (int kb = 0; kb < 16; kb++)
                nax = __builtin_amdgcn_mfma_f32_16x16x32_bf16(ld_bf8(xp + kb * 32), ld_bf8(wxp + kb * 32), nax, 0, 0, 0);
            if (g == 1) {
                unsigned int tgt = (unsigned int)(t + 1);
                while (!__all(__hip_atomic_load(flA, __ATOMIC_RELAXED, __HIP_MEMORY_SCOPE_AGENT) >= tgt))
                    __builtin_amdgcn_s_sleep(1);
                __hip_atomic_store(go, 2u * (unsigned)t + 2u, __ATOMIC_RELAXED, __HIP_MEMORY_SCOPE_WORKGROUP);
            } else {
                unsigned int tgtg = 2u * (unsigned)t + 2u;
                while (__hip_atomic_load(go, __ATOMIC_RELAXED, __HIP_MEMORY_SCOPE_WORKGROUP) < tgtg)
                    __builtin_amdgcn_s_sleep(1);
            }
            asm volatile("" ::: "memory");   // pin next iter's half-A stage behind the gate
        }
        ax = nax;
    }
}

// ---------------- host ----------------
extern "C" void kernel_launch(void* const* d_in, const int* in_sizes, int n_in,
                              void* d_out, int out_size, void* d_ws, size_t ws_size,
                              hipStream_t stream) {
    const float* x   = (const float*)d_in[0];
    const float* Wxz = (const float*)d_in[1];
    const float* bxz = (const float*)d_in[2];
    const float* Whz = (const float*)d_in[3];
    const float* bhz = (const float*)d_in[4];
    const float* Wxr = (const float*)d_in[5];
    const float* bxr = (const float*)d_in[6];
    const float* Whr = (const float*)d_in[7];
    const float* bhr = (const float*)d_in[8];
    const float* Wxh = (const float*)d_in[9];
    const float* bxh = (const float*)d_in[10];
    const float* Whh = (const float*)d_in[11];
    const float* bhh = (const float*)d_in[12];
    const float* Why = (const float*)d_in[13];
    const float* bhy = (const float*)d_in[14];

    char* ws = (char*)d_ws;
    size_t off = 0;
    auto alloc = [&](size_t bytes) { char* p = ws + off; off += (bytes + 255) & ~(size_t)255; return p; };
    unsigned short* Whc   = (unsigned short*)alloc((size_t)3 * HID * HID * 2);
    unsigned short* Wxc   = (unsigned short*)alloc((size_t)3 * HID * INF * 2);
    unsigned short* Whyb  = (unsigned short*)alloc((size_t)OUTF * HID * 2);
    float*          bias2 = (float*)alloc((size_t)2 * HID * 4);
    unsigned short* hsFM  = (unsigned short*)alloc((size_t)(SEQL + 1) * 65536 * 2); // 65.7 MB FM h
    unsigned int*   flags = (unsigned int*)alloc(1024);
    unsigned short* x_bf  = (unsigned short*)d_out;  // dead until the final GEMM

    if (off > ws_size) {
        fail_sentinel<<<dim3(1), dim3(1), 0, stream>>>((float*)d_out);
        return;
    }

    auto cvt = [&](const float* s, unsigned short* d, size_t n) {
        cvt_f32_bf16<<<dim3((unsigned)((n / 4 + 255) / 256)), dim3(256), 0, stream>>>(s, d, (int)n);
    };
    cvt(x, x_bf, (size_t)SB * INF);
    cvt(Whz, Whc, (size_t)HID * HID);
    cvt(Whr, Whc + (size_t)HID * HID, (size_t)HID * HID);
    cvt(Whh, Whc + (size_t)2 * HID * HID, (size_t)HID * HID);
    cvt(Wxz, Wxc, (size_t)HID * INF);
    cvt(Wxr, Wxc + (size_t)HID * INF, (size_t)HID * INF);
    cvt(Wxh, Wxc + (size_t)2 * HID * INF, (size_t)HID * INF);
    cvt(Why, Whyb, (size_t)OUTF * HID);
    make_bias2<<<dim3(8), dim3(256), 0, stream>>>(bxz, bhz, bxr, bhr, bias2);
    (void)hipMemsetAsync(flags, 0, 1024, stream);   // reset per launch (graph-replay safe)

    gru_scan<<<dim3(256), dim3(192), 0, stream>>>(Whc, Wxc, x_bf, hsFM, bias2, bxh, bhh, flags);

    // out[SB, O] = hs[1..512] @ Why^T + bhy ; A read from FM layout (t=1 block onward)
    gemm_nt_f32<<<dim3((SB / 128) * (OUTF / 128)), dim3(256), 0, stream>>>(
        hsFM + 65536, Whyb, HID, bhy, (float*)d_out, OUTF, HID);
}